// Round 9
// baseline (88.460 us; speedup 1.0000x reference)
//
#include <hip/hip_runtime.h>

// ModelInverse: invert monotone MLP CDF F(x) for 2M targets.
// R9: consolidation (3 dispatches).
//  - fused_build: T[j] = A(j/TSZ) on 2^12+1 grid (halved from R8; T-lerp
//    error <= ~5e-5 in x, far under the 0.0039 bf16 compare floor).
//  - invert_kernel: G[k] = F^-1(k/GSZ) on 2^14+1 z-grid, 12-step search on
//    L1-resident T (16 KB).
//  - apply: NO LDS staging (R8 spent ~16 staging iters vs ~4 sample iters
//    per thread). Direct L2 gather of G (64 KB, dispatch-coherent), high
//    occupancy (no LDS cap), grid-stride float4.
//
// ws layout (floats): T[TSZ+1] @0 | G[GSZ+1] @4100 (16B aligned).

#define MONO 1e-3f
#define TLOG2 12
#define TSZ (1 << TLOG2)   // forward table: T[0..TSZ]
#define GLOG2 14
#define GSZ (1 << GLOG2)   // inverse table: G[0..GSZ]
#define WS_G 4100          // float offset of G (TSZ+1=4097, pad to 16B)

typedef float fvec64 __attribute__((ext_vector_type(64)));

__device__ __forceinline__ float fast_rcp(float x) {
#if __has_builtin(__builtin_amdgcn_rcpf)
    return __builtin_amdgcn_rcpf(x);   // v_rcp_f32, ~1 ulp
#else
    return 1.0f / x;
#endif
}

__device__ __forceinline__ float sigmoidf_(float t) {
    return fast_rcp(1.0f + __expf(-t));   // v_mul+v_exp+v_add+v_rcp
}

// T[j] = sigmoid(w3 . sigmoid(W2 . sigmoid(x*w1+b1) + b2) + b3) + MONO*x
// Block = 256 = 4 waves; wave `sub` handles rows [16*sub, 16*sub+16) for 64
// entries (lane = entry). exp(pw2) staged into LDS by the whole block.
__global__ __launch_bounds__(256, 4) void fused_build_kernel(
        const float* __restrict__ pw1,
        const float* __restrict__ b1,
        const float* __restrict__ pw2,
        const float* __restrict__ b2,
        const float* __restrict__ pw3,
        const float* __restrict__ b3,
        float* __restrict__ T) {
    __shared__ __align__(16) float W2s[4096];
    __shared__ float part[256];

    int tid  = threadIdx.x;
#pragma unroll
    for (int i = 0; i < 16; ++i) {
        int idx = tid + i * 256;
        W2s[idx] = __expf(pw2[idx]);
    }
    __syncthreads();

    int lane = tid & 63;
    int sub = __builtin_amdgcn_readfirstlane(tid >> 6);   // 0..3, SGPR
    int j = blockIdx.x * 64 + lane;
    int jc = j <= TSZ ? j : TSZ;
    float x = (float)jc * (1.0f / (float)TSZ);

    fvec64 h1;    // SSA vector: cannot be demoted/remat'd
#pragma unroll
    for (int k = 0; k < 64; ++k)
        h1[k] = sigmoidf_(fmaf(x, __expf(pw1[k]), b1[k]));

    float acc3 = 0.0f;
#pragma unroll
    for (int r = 0; r < 16; ++r) {
        int row = sub * 16 + r;        // uniform -> s_load / uniform ds addr
        float acc = b2[row];
        const float4* __restrict__ w4 =
            reinterpret_cast<const float4*>(&W2s[row * 64]);
#pragma unroll
        for (int q = 0; q < 16; ++q) { // ds_read_b128 broadcast
            float4 w = w4[q];
            acc = fmaf(w.x, h1[4 * q + 0], acc);
            acc = fmaf(w.y, h1[4 * q + 1], acc);
            acc = fmaf(w.z, h1[4 * q + 2], acc);
            acc = fmaf(w.w, h1[4 * q + 3], acc);
        }
        acc3 = fmaf(__expf(pw3[row]), sigmoidf_(acc), acc3);
    }

    part[sub * 64 + lane] = acc3;
    __syncthreads();
    if (tid < 64 && j <= TSZ) {
        float s = part[lane] + part[64 + lane] + part[128 + lane]
                + part[192 + lane] + b3[0];
        T[j] = sigmoidf_(s) + MONO * x;
    }
}

// G[k] = x with F(x) = k/GSZ: exact 12-step binary search on T + lerp.
__global__ __launch_bounds__(256) void invert_kernel(
        const float* __restrict__ T,
        float* __restrict__ G) {
    int k = blockIdx.x * blockDim.x + threadIdx.x;
    if (k > GSZ) return;
    float a0 = T[0];
    float a1 = T[TSZ];
    float zt = fmaf((float)k * (1.0f / (float)GSZ), a1 - a0, a0);

    int lo = 0;
#pragma unroll
    for (int s = TSZ >> 1; s >= 1; s >>= 1) {
        int c = lo + s;                // c <= TSZ-1
        if (T[c] <= zt) lo = c;
    }
    float tl = T[lo];
    float th = T[lo + 1];
    float d = th - tl;
    float t = (d > 1e-30f) ? (zt - tl) * fast_rcp(d) : 0.5f;
    t = fminf(fmaxf(t, 0.0f), 1.0f);
    G[k] = ((float)lo + t) * (1.0f / (float)TSZ);
}

__device__ __forceinline__ float lerp_one(float zv, const float* __restrict__ G) {
    float u = fminf(fmaxf(zv, 0.0f), 1.0f) * (float)GSZ;
    int k = (int)u; k = k > GSZ - 1 ? GSZ - 1 : k;
    float g0 = G[k];
    float g1 = G[k + 1];
    return fmaf(u - (float)k, g1 - g0, g0);
}

#define APPLY_BLOCKS 1024

__global__ __launch_bounds__(256) void apply_kernel(
        const float* __restrict__ z,
        const float* __restrict__ G,
        float* __restrict__ out, int n) {
    int tid = threadIdx.x;
    int nv = n >> 2;
    int stride = gridDim.x * 256;
    for (int idx = blockIdx.x * 256 + tid; idx < nv; idx += stride) {
        float4 zz = reinterpret_cast<const float4*>(z)[idx];
        float4 oo;
        oo.x = lerp_one(zz.x, G);
        oo.y = lerp_one(zz.y, G);
        oo.z = lerp_one(zz.z, G);
        oo.w = lerp_one(zz.w, G);
        reinterpret_cast<float4*>(out)[idx] = oo;
    }
    int base = nv * 4;
    for (int t = base + blockIdx.x * 256 + tid; t < n; t += stride)
        out[t] = lerp_one(z[t], G);
}

extern "C" void kernel_launch(void* const* d_in, const int* in_sizes, int n_in,
                              void* d_out, int out_size, void* d_ws, size_t ws_size,
                              hipStream_t stream) {
    const float* z   = (const float*)d_in[0];
    const float* pw1 = (const float*)d_in[1];
    const float* b1  = (const float*)d_in[2];
    const float* pw2 = (const float*)d_in[3];
    const float* b2  = (const float*)d_in[4];
    const float* pw3 = (const float*)d_in[5];
    const float* b3  = (const float*)d_in[6];
    float* out = (float*)d_out;
    float* T   = (float*)d_ws;
    float* G   = (float*)d_ws + WS_G;
    int n = in_sizes[0];

    fused_build_kernel<<<(TSZ + 1 + 63) / 64, 256, 0, stream>>>(
        pw1, b1, pw2, b2, pw3, b3, T);
    invert_kernel<<<(GSZ + 1 + 255) / 256, 256, 0, stream>>>(T, G);
    apply_kernel<<<APPLY_BLOCKS, 256, 0, stream>>>(z, G, out, n);
}

// Round 10
// 85.540 us; speedup vs baseline: 1.0341x; 1.0341x over previous
//
#include <hip/hip_runtime.h>

// ModelInverse: invert monotone MLP CDF F(x) for 2M targets.
// R10: best-measured combination of R8+R9 (3 dispatches).
//  - fused_build: T[j] = A(j/TSZ) on 2^12+1 grid (R9, safe: T-lerp error
//    <= ~5e-5 in x, far under the 0.0039 compare floor).
//  - invert_kernel: G[k] = F^-1(k/GSZ) on 2^14+1 z-grid, 12-step search on
//    L1-resident T (16 KB).
//  - apply: R8's LDS-staged form (proven 4 us): stage G (64 KB, 2 blk/CU),
//    per sample = 1 mul + 2 ds_read + 1 fma. R9's no-stage L2-gather
//    variant measured +4 us worse -- scattered ~200-cyc L2 hits lose to a
//    coalesced one-time stage + LDS-latency lookups.
//
// ws layout (floats): T[TSZ+1] @0 | G[GSZ+1] @4100 (16B aligned).

#define MONO 1e-3f
#define TLOG2 12
#define TSZ (1 << TLOG2)   // forward table: T[0..TSZ]
#define GLOG2 14
#define GSZ (1 << GLOG2)   // inverse table: G[0..GSZ]
#define WS_G 4100          // float offset of G (TSZ+1=4097, pad to 16B)

typedef float fvec64 __attribute__((ext_vector_type(64)));

__device__ __forceinline__ float fast_rcp(float x) {
#if __has_builtin(__builtin_amdgcn_rcpf)
    return __builtin_amdgcn_rcpf(x);   // v_rcp_f32, ~1 ulp
#else
    return 1.0f / x;
#endif
}

__device__ __forceinline__ float sigmoidf_(float t) {
    return fast_rcp(1.0f + __expf(-t));   // v_mul+v_exp+v_add+v_rcp
}

// T[j] = sigmoid(w3 . sigmoid(W2 . sigmoid(x*w1+b1) + b2) + b3) + MONO*x
// Block = 256 = 4 waves; wave `sub` handles rows [16*sub, 16*sub+16) for 64
// entries (lane = entry). exp(pw2) staged into LDS by the whole block.
__global__ __launch_bounds__(256, 4) void fused_build_kernel(
        const float* __restrict__ pw1,
        const float* __restrict__ b1,
        const float* __restrict__ pw2,
        const float* __restrict__ b2,
        const float* __restrict__ pw3,
        const float* __restrict__ b3,
        float* __restrict__ T) {
    __shared__ __align__(16) float W2s[4096];
    __shared__ float part[256];

    int tid  = threadIdx.x;
#pragma unroll
    for (int i = 0; i < 16; ++i) {
        int idx = tid + i * 256;
        W2s[idx] = __expf(pw2[idx]);
    }
    __syncthreads();

    int lane = tid & 63;
    int sub = __builtin_amdgcn_readfirstlane(tid >> 6);   // 0..3, SGPR
    int j = blockIdx.x * 64 + lane;
    int jc = j <= TSZ ? j : TSZ;
    float x = (float)jc * (1.0f / (float)TSZ);

    fvec64 h1;    // SSA vector: cannot be demoted/remat'd
#pragma unroll
    for (int k = 0; k < 64; ++k)
        h1[k] = sigmoidf_(fmaf(x, __expf(pw1[k]), b1[k]));

    float acc3 = 0.0f;
#pragma unroll
    for (int r = 0; r < 16; ++r) {
        int row = sub * 16 + r;        // uniform -> s_load / uniform ds addr
        float acc = b2[row];
        const float4* __restrict__ w4 =
            reinterpret_cast<const float4*>(&W2s[row * 64]);
#pragma unroll
        for (int q = 0; q < 16; ++q) { // ds_read_b128 broadcast
            float4 w = w4[q];
            acc = fmaf(w.x, h1[4 * q + 0], acc);
            acc = fmaf(w.y, h1[4 * q + 1], acc);
            acc = fmaf(w.z, h1[4 * q + 2], acc);
            acc = fmaf(w.w, h1[4 * q + 3], acc);
        }
        acc3 = fmaf(__expf(pw3[row]), sigmoidf_(acc), acc3);
    }

    part[sub * 64 + lane] = acc3;
    __syncthreads();
    if (tid < 64 && j <= TSZ) {
        float s = part[lane] + part[64 + lane] + part[128 + lane]
                + part[192 + lane] + b3[0];
        T[j] = sigmoidf_(s) + MONO * x;
    }
}

// G[k] = x with F(x) = k/GSZ: exact 12-step binary search on T + lerp.
__global__ __launch_bounds__(256) void invert_kernel(
        const float* __restrict__ T,
        float* __restrict__ G) {
    int k = blockIdx.x * blockDim.x + threadIdx.x;
    if (k > GSZ) return;
    float a0 = T[0];
    float a1 = T[TSZ];
    float zt = fmaf((float)k * (1.0f / (float)GSZ), a1 - a0, a0);

    int lo = 0;
#pragma unroll
    for (int s = TSZ >> 1; s >= 1; s >>= 1) {
        int c = lo + s;                // c <= TSZ-1
        if (T[c] <= zt) lo = c;
    }
    float tl = T[lo];
    float th = T[lo + 1];
    float d = th - tl;
    float t = (d > 1e-30f) ? (zt - tl) * fast_rcp(d) : 0.5f;
    t = fminf(fmaxf(t, 0.0f), 1.0f);
    G[k] = ((float)lo + t) * (1.0f / (float)TSZ);
}

#define APPLY_BLOCKS 512   // 64 KB LDS -> 2 blocks/CU

__global__ __launch_bounds__(256) void apply_kernel(
        const float* __restrict__ z,
        const float* __restrict__ G,
        float* __restrict__ out, int n) {
    __shared__ __align__(16) float Gs[GSZ + 4];
    int tid = threadIdx.x;
#pragma unroll
    for (int i = 0; i < (GSZ / 4) / 256; ++i) {      // 16 float4 iters
        int idx = tid + i * 256;
        reinterpret_cast<float4*>(Gs)[idx] =
            reinterpret_cast<const float4*>(G)[idx];
    }
    if (tid == 0) Gs[GSZ] = G[GSZ];
    __syncthreads();

    int nv = n >> 2;
    int stride = gridDim.x * 256;
    for (int idx = blockIdx.x * 256 + tid; idx < nv; idx += stride) {
        float4 zz = reinterpret_cast<const float4*>(z)[idx];
        float4 oo;
        {
            float u = fminf(fmaxf(zz.x, 0.0f), 1.0f) * (float)GSZ;
            int k = (int)u; k = k > GSZ - 1 ? GSZ - 1 : k;
            oo.x = fmaf(u - (float)k, Gs[k + 1] - Gs[k], Gs[k]);
        }
        {
            float u = fminf(fmaxf(zz.y, 0.0f), 1.0f) * (float)GSZ;
            int k = (int)u; k = k > GSZ - 1 ? GSZ - 1 : k;
            oo.y = fmaf(u - (float)k, Gs[k + 1] - Gs[k], Gs[k]);
        }
        {
            float u = fminf(fmaxf(zz.z, 0.0f), 1.0f) * (float)GSZ;
            int k = (int)u; k = k > GSZ - 1 ? GSZ - 1 : k;
            oo.z = fmaf(u - (float)k, Gs[k + 1] - Gs[k], Gs[k]);
        }
        {
            float u = fminf(fmaxf(zz.w, 0.0f), 1.0f) * (float)GSZ;
            int k = (int)u; k = k > GSZ - 1 ? GSZ - 1 : k;
            oo.w = fmaf(u - (float)k, Gs[k + 1] - Gs[k], Gs[k]);
        }
        reinterpret_cast<float4*>(out)[idx] = oo;
    }
    int base = nv * 4;
    for (int t = base + blockIdx.x * 256 + tid; t < n; t += stride) {
        float u = fminf(fmaxf(z[t], 0.0f), 1.0f) * (float)GSZ;
        int k = (int)u; k = k > GSZ - 1 ? GSZ - 1 : k;
        out[t] = fmaf(u - (float)k, Gs[k + 1] - Gs[k], Gs[k]);
    }
}

extern "C" void kernel_launch(void* const* d_in, const int* in_sizes, int n_in,
                              void* d_out, int out_size, void* d_ws, size_t ws_size,
                              hipStream_t stream) {
    const float* z   = (const float*)d_in[0];
    const float* pw1 = (const float*)d_in[1];
    const float* b1  = (const float*)d_in[2];
    const float* pw2 = (const float*)d_in[3];
    const float* b2  = (const float*)d_in[4];
    const float* pw3 = (const float*)d_in[5];
    const float* b3  = (const float*)d_in[6];
    float* out = (float*)d_out;
    float* T   = (float*)d_ws;
    float* G   = (float*)d_ws + WS_G;
    int n = in_sizes[0];

    fused_build_kernel<<<(TSZ + 1 + 63) / 64, 256, 0, stream>>>(
        pw1, b1, pw2, b2, pw3, b3, T);
    invert_kernel<<<(GSZ + 1 + 255) / 256, 256, 0, stream>>>(T, G);
    apply_kernel<<<APPLY_BLOCKS, 256, 0, stream>>>(z, G, out, n);
}